// Round 6
// baseline (17516.902 us; speedup 1.0000x reference)
//
#include <hip/hip_runtime.h>
#include <hip/hip_bf16.h>

typedef float f32x4 __attribute__((ext_vector_type(4)));
typedef short bf16x8 __attribute__((ext_vector_type(8)));

#define MFMA16x32(a,b,c) __builtin_amdgcn_mfma_f32_16x16x32_bf16((a),(b),(c),0,0,0)

__device__ __forceinline__ unsigned short f2bf(float f) {
  unsigned u = __float_as_uint(f);
  u += 0x7fffu + ((u >> 16) & 1u);
  return (unsigned short)(u >> 16);
}

// ---- agent-scope (sc0 sc1: L1/L2-bypass, L3-coherent) data movement, fence-free ----
__device__ __forceinline__ void ast16(unsigned short* p, unsigned short v) {
  __hip_atomic_store(p, v, __ATOMIC_RELAXED, __HIP_MEMORY_SCOPE_AGENT);
}
__device__ __forceinline__ bf16x8 ldfrag(const unsigned short* p) {
  union { unsigned long long u[2]; bf16x8 v; } x;
  x.u[0] = __hip_atomic_load((const unsigned long long*)p,     __ATOMIC_RELAXED, __HIP_MEMORY_SCOPE_AGENT);
  x.u[1] = __hip_atomic_load((const unsigned long long*)(p+4), __ATOMIC_RELAXED, __HIP_MEMORY_SCOPE_AGENT);
  return x.v;
}

// ---------------- workspace layout (bytes) ----------------
// g1blob 8MB | g3blob 16MB | woutT 8MB | h1ring 4x128KB | sync 16KB | h2all 32MB
#define WS_G1BLOB 0ull
#define WS_G3BLOB 8388608ull
#define WS_WOUTT  25165824ull
#define WS_H1RING 33554432ull
#define WS_SYNC   34078720ull
#define WS_H2ALL  34095104ull

#define SLSTRIDE 16   // u32 per sync slot (one 64B line per block)

// ---------------- init: zero sync region ----------------
__global__ void k_init(unsigned* __restrict__ p, int n) {
  int i = blockIdx.x * blockDim.x + threadIdx.x;
  for (; i < n; i += gridDim.x * blockDim.x) p[i] = 0u;
}

// ---------------- pack W1h into per-wave B-fragment blob ----------------
__global__ void k_pack_g1(const float* __restrict__ W1, unsigned short* __restrict__ blob) {
  int gtid = blockIdx.x * 256 + threadIdx.x;      // 524288 threads
  int lane = gtid & 63, kk = (gtid >> 6) & 31, w = gtid >> 11;
  int c = lane & 15, q = lane >> 4;
  int g = c >> 2, h = w * 4 + (c & 3);
  bf16x8 s;
#pragma unroll
  for (int j = 0; j < 8; ++j) {
    int k = kk * 32 + q * 8 + j;
    float v = W1[(size_t)g * 5242880u + (size_t)(4096 + k) * 1024u + h];
    ((unsigned short*)&s)[j] = f2bf(v);
  }
  ((bf16x8*)blob)[(size_t)(w * 32 + kk) * 64 + lane] = s;
}

// ---------------- pack W2 (kk<32 -> W2h rows 1024+, kk>=32 -> W2x rows 0..1023) ----------------
__global__ void k_pack_g3(const float* __restrict__ W2, unsigned short* __restrict__ blob) {
  int gtid = blockIdx.x * 256 + threadIdx.x;      // 1048576 threads
  int lane = gtid & 63, kk = (gtid >> 6) & 63, w = gtid >> 12;
  int c = lane & 15, q = lane >> 4;
  int g = c >> 2, h = w * 4 + (c & 3);
  bf16x8 s;
#pragma unroll
  for (int j = 0; j < 8; ++j) {
    int klocal = (kk & 31) * 32 + q * 8 + j;
    int d = (kk < 32) ? (1024 + klocal) : klocal;
    float v = W2[(size_t)g * 2097152u + (size_t)d * 1024u + h];
    ((unsigned short*)&s)[j] = f2bf(v);
  }
  ((bf16x8*)blob)[(size_t)(w * 64 + kk) * 64 + lane] = s;
}

// ---------------- Wout^T bf16 ----------------
__global__ void k_pack_woutT(const float* __restrict__ Wout, unsigned short* __restrict__ wT) {
  int gtid = blockIdx.x * 256 + threadIdx.x;      // 4,194,304 threads
  int k = gtid & 1023, n = gtid >> 10;
  wT[(size_t)n * 1024 + k] = f2bf(Wout[(size_t)k * 4096 + n]);
}

// ---------------- flag-array sync primitives (fence-free) ----------------
// Wait until all 64 slots >= epoch. Wave 0: lane i polls slot i (RELAXED agent
// load = L2-bypass read from L3; nothing stale to invalidate since ALL shared
// data moves via agent-scope ops). Block-wide sync via syncthreads.
__device__ __forceinline__ void wait_slots(const unsigned* __restrict__ slots,
                                           unsigned epoch, unsigned* __restrict__ poison) {
  if (threadIdx.x < 64) {
    unsigned guard = 0;
    for (;;) {
      unsigned v = __hip_atomic_load(&slots[threadIdx.x * SLSTRIDE],
                                     __ATOMIC_RELAXED, __HIP_MEMORY_SCOPE_AGENT);
      if (__all((int)(v >= epoch))) break;
      __builtin_amdgcn_s_sleep(2);
      if (((++guard) & 1023u) == 0u) {
        if (guard > (1u << 18) ||
            __hip_atomic_load(poison, __ATOMIC_RELAXED, __HIP_MEMORY_SCOPE_AGENT) != 0u) {
          __hip_atomic_store(poison, 1u, __ATOMIC_RELAXED, __HIP_MEMORY_SCOPE_AGENT);
          break;   // fail-visible, never hard-hang
        }
      }
    }
  }
  __syncthreads();
}

// Publish: every thread drains its own write-through stores (vmcnt(0) — they are
// then globally visible at L3), block barrier, thread 0 stores the flag. No L2
// writeback anywhere.
__device__ __forceinline__ void publish_slot(unsigned* __restrict__ slots,
                                             int myslot, unsigned epoch) {
  asm volatile("s_waitcnt vmcnt(0)" ::: "memory");
  __syncthreads();
  if (threadIdx.x == 0) {
    __hip_atomic_store(&slots[myslot * SLSTRIDE], epoch,
                       __ATOMIC_RELAXED, __HIP_MEMORY_SCOPE_AGENT);
  }
}

// ---------------- persistent recurrent kernel (128 blocks, two decoupled groups) ----------------
// G1 (blocks 0..63):  H1(t) = ew(gather + H1(t-1)@W1h + b1) -> h1ring[t&3]; barrier among G1 only.
// G3 (blocks 64..127): H2(t) = ew(b2 + H2(t-1)@W2h + H1(t)@W2x) -> h2all[t]; barrier among G3;
//                      waits on G1's slots for H1(t); G1 backpressured to <=3 steps ahead.
__global__ __launch_bounds__(256, 1) void k_lstm(
    const int* __restrict__ tokens, const float* __restrict__ W1,
    const float* __restrict__ b1, const float* __restrict__ b2,
    const unsigned short* __restrict__ g1blob, const unsigned short* __restrict__ g3blob,
    unsigned short* __restrict__ h1ring, unsigned short* __restrict__ h2all,
    float* __restrict__ outF, unsigned* __restrict__ syncbase)
{
  const int tid = threadIdx.x, lane = tid & 63, widx = tid >> 6, bid = blockIdx.x;
  const int c = lane & 15, q = lane >> 4;
  const bool isG1 = bid < 64;
  const int myslot = isG1 ? bid : bid - 64;
  const int w = myslot * 4 + widx;                    // 0..255 within role
  const int g = c >> 2;
  const int hcol = w * 4 + (c & 3);
  const int h_ew = w * 4 + (lane & 3);

  unsigned* g1slots = syncbase;                       // 64 x 16 u32
  unsigned* g3slots = syncbase + 1024;
  unsigned* poison  = syncbase + 2048;

  // --- preload weight fragments into registers ---
  bf16x8 Breg[64];
  {
    const bf16x8* blob1 = (const bf16x8*)g1blob;
    const bf16x8* blob3 = (const bf16x8*)g3blob;
#pragma unroll
    for (int kk = 0; kk < 32; ++kk)
      Breg[kk] = isG1 ? blob1[(size_t)(w * 32 + kk) * 64 + lane]
                      : blob3[(size_t)(w * 64 + kk) * 64 + lane];
    if (!isG1) {
#pragma unroll
      for (int kk = 32; kk < 64; ++kk)
        Breg[kk] = blob3[(size_t)(w * 64 + kk) * 64 + lane];
    }
  }
  const float biasv = isG1 ? b1[g * 1024 + hcol] : b2[g * 1024 + hcol];

  float Cst[16];
#pragma unroll
  for (int i = 0; i < 16; ++i) Cst[i] = 0.f;

  // --- G1: preload embedding gathers for t=0 ---
  float gv[16];
  if (isG1) {
#pragma unroll
    for (int m = 0; m < 4; ++m)
#pragma unroll
      for (int r = 0; r < 4; ++r) {
        int b_ = m * 16 + q * 4 + r;
        int tk = tokens[b_ * 256];
        gv[m * 4 + r] = W1[(size_t)g * 5242880u + (size_t)tk * 1024u + hcol];
      }
  }

  f32x4 acc[4];

  if (isG1) {
    // ================= G1 chain =================
#pragma clang loop unroll(disable)
    for (int t = 0; t < 256; ++t) {
      if (t > 0) wait_slots(g1slots, (unsigned)t, poison);   // group barrier (all H1(t-1) visible)

      int tk2[16];
      const int tn = (t < 255) ? t + 1 : 255;
#pragma unroll
      for (int m = 0; m < 4; ++m)
#pragma unroll
        for (int r = 0; r < 4; ++r)
          tk2[m * 4 + r] = tokens[(m * 16 + q * 4 + r) * 256 + tn];

#pragma unroll
      for (int m = 0; m < 4; ++m) acc[m] = (f32x4){0.f, 0.f, 0.f, 0.f};
      if (t > 0) {
        const unsigned short* Hrd = h1ring + ((t - 1) & 3) * 65536;
#pragma unroll
        for (int kk = 0; kk < 32; ++kk) {
#pragma unroll
          for (int m = 0; m < 4; ++m) {
            bf16x8 a = ldfrag(Hrd + (m * 16 + c) * 1024 + kk * 32 + q * 8);
            acc[m] = MFMA16x32(a, Breg[kk], acc[m]);
          }
        }
      }
      if (t >= 4) wait_slots(g3slots, (unsigned)(t - 3), poison);  // ring backpressure

#pragma unroll
      for (int m = 0; m < 4; ++m) {
#pragma unroll
        for (int r = 0; r < 4; ++r) {
          float v = acc[m][r] + gv[m * 4 + r] + biasv;
          const int sb = (lane & 48) | (lane & 3);
          float vf = __shfl(v, sb, 64);
          float vi = __shfl(v, sb | 4, 64);
          float vo = __shfl(v, sb | 8, 64);
          float vc = __shfl(v, sb | 12, 64);
          float fg = 1.f / (1.f + __expf(-vf));
          float ig = 1.f / (1.f + __expf(-vi));
          float og = 1.f / (1.f + __expf(-vo));
          float e2 = __expf(2.f * vc);
          float ct = (e2 - 1.f) / (e2 + 1.f);
          float Cn = fg * Cst[m * 4 + r] + ig * ct;
          Cst[m * 4 + r] = Cn;
          float e2c = __expf(2.f * Cn);
          float Hn = og * (e2c - 1.f) / (e2c + 1.f);
          if ((lane & 12) == 0) {
            int row = m * 16 + q * 4 + r;
            ast16(&h1ring[(t & 3) * 65536 + row * 1024 + h_ew], f2bf(Hn));
            if (t == 255) {
              outF[row * 1024 + h_ew] = Hn;           // H1 final
              outF[65536 + row * 1024 + h_ew] = Cn;   // C1 final
            }
          }
        }
      }
      publish_slot(g1slots, myslot, (unsigned)(t + 1));      // H1(t) published

      // prefetch next step's embedding gathers (overlaps barrier wait)
#pragma unroll
      for (int i = 0; i < 16; ++i)
        gv[i] = W1[(size_t)g * 5242880u + (size_t)tk2[i] * 1024u + hcol];
    }
  } else {
    // ================= G3 chain =================
#pragma clang loop unroll(disable)
    for (int t = 0; t < 256; ++t) {
      if (t > 0) wait_slots(g3slots, (unsigned)t, poison);   // group barrier (all H2(t-1) visible)

#pragma unroll
      for (int m = 0; m < 4; ++m) acc[m] = (f32x4){biasv, biasv, biasv, biasv};
      if (t > 0) {
        const unsigned short* Hrd = h2all + (size_t)(t - 1) * 65536;
#pragma unroll
        for (int kk = 0; kk < 32; ++kk) {
#pragma unroll
          for (int m = 0; m < 4; ++m) {
            bf16x8 a = ldfrag(Hrd + (m * 16 + c) * 1024 + kk * 32 + q * 8);
            acc[m] = MFMA16x32(a, Breg[kk], acc[m]);
          }
        }
      }

      wait_slots(g1slots, (unsigned)(t + 1), poison);        // H1(t) available (G1 runs ahead)
      {
        const unsigned short* Hrd = h1ring + (t & 3) * 65536;
#pragma unroll
        for (int kk = 32; kk < 64; ++kk) {
#pragma unroll
          for (int m = 0; m < 4; ++m) {
            bf16x8 a = ldfrag(Hrd + (m * 16 + c) * 1024 + (kk - 32) * 32 + q * 8);
            acc[m] = MFMA16x32(a, Breg[kk], acc[m]);
          }
        }
      }

#pragma unroll
      for (int m = 0; m < 4; ++m) {
#pragma unroll
        for (int r = 0; r < 4; ++r) {
          float v = acc[m][r];
          const int sb = (lane & 48) | (lane & 3);
          float vf = __shfl(v, sb, 64);
          float vi = __shfl(v, sb | 4, 64);
          float vo = __shfl(v, sb | 8, 64);
          float vc = __shfl(v, sb | 12, 64);
          float fg = 1.f / (1.f + __expf(-vf));
          float ig = 1.f / (1.f + __expf(-vi));
          float og = 1.f / (1.f + __expf(-vo));
          float e2 = __expf(2.f * vc);
          float ct = (e2 - 1.f) / (e2 + 1.f);
          float Cn = fg * Cst[m * 4 + r] + ig * ct;
          Cst[m * 4 + r] = Cn;
          float e2c = __expf(2.f * Cn);
          float Hn = og * (e2c - 1.f) / (e2c + 1.f);
          if ((lane & 12) == 0) {
            int row = m * 16 + q * 4 + r;
            ast16(&h2all[((size_t)t * 64 + row) * 1024 + h_ew], f2bf(Hn));
            if (t == 255) {
              outF[131072 + row * 1024 + h_ew] = Hn;  // H2 final
              outF[196608 + row * 1024 + h_ew] = Cn;  // C2 final
            }
          }
        }
      }
      publish_slot(g3slots, myslot, (unsigned)(t + 1));      // H2(t) published
    }
  }
}

// ---------------- output projection: Y = H2all @ Wout + bout ----------------
__global__ __launch_bounds__(256, 2) void k_gemm_out(
    const unsigned short* __restrict__ A, const unsigned short* __restrict__ Bt,
    const float* __restrict__ bout, float* __restrict__ C)
{
  __shared__ unsigned short As[128 * 32];
  __shared__ unsigned short Bs[128 * 32];
  const int tid = threadIdx.x, lane = tid & 63, wv = tid >> 6;
  const int c = lane & 15, q = lane >> 4;
  const int bn = blockIdx.x & 31, bm = blockIdx.x >> 5;
  const int wm = wv >> 1, wn = wv & 1;

  f32x4 acc[4][4];
#pragma unroll
  for (int m = 0; m < 4; ++m)
#pragma unroll
    for (int n = 0; n < 4; ++n) acc[m][n] = (f32x4){0.f, 0.f, 0.f, 0.f};

  const unsigned short* Abase = A + (size_t)(bm * 128) * 1024;
  const unsigned short* Bbase = Bt + (size_t)(bn * 128) * 1024;

  for (int kt = 0; kt < 32; ++kt) {
    if (kt) __syncthreads();
#pragma unroll
    for (int ch = 0; ch < 2; ++ch) {
      int o = ch * 4096 + tid * 16;          // byte offset within 8KB tile
      int row = o >> 6;
      int ks = (o & 63) >> 1;
      *(bf16x8*)&As[o >> 1] = *(const bf16x8*)(Abase + (size_t)row * 1024 + kt * 32 + ks);
      *(bf16x8*)&Bs[o >> 1] = *(const bf16x8*)(Bbase + (size_t)row * 1024 + kt * 32 + ks);
    }
    __syncthreads();
    bf16x8 af[4], bfr[4];
#pragma unroll
    for (int m = 0; m < 4; ++m) af[m] = *(const bf16x8*)&As[(wm * 64 + m * 16 + c) * 32 + q * 8];
#pragma unroll
    for (int n = 0; n < 4; ++n) bfr[n] = *(const bf16x8*)&Bs[(wn * 64 + n * 16 + c) * 32 + q * 8];
#pragma unroll
    for (int m = 0; m < 4; ++m)
#pragma unroll
      for (int n = 0; n < 4; ++n) acc[m][n] = MFMA16x32(af[m], bfr[n], acc[m][n]);
  }

#pragma unroll
  for (int n = 0; n < 4; ++n) {
    int col = bn * 128 + wn * 64 + n * 16 + c;
    float bo = bout[col];
#pragma unroll
    for (int m = 0; m < 4; ++m) {
      int row0 = bm * 128 + wm * 64 + m * 16 + q * 4;
#pragma unroll
      for (int r = 0; r < 4; ++r)
        C[(size_t)(row0 + r) * 4096 + col] = acc[m][n][r] + bo;
    }
  }
}

extern "C" void kernel_launch(void* const* d_in, const int* in_sizes, int n_in,
                              void* d_out, int out_size, void* d_ws, size_t ws_size,
                              hipStream_t stream) {
  const int* tokens = (const int*)d_in[0];
  const float* W1 = (const float*)d_in[1];
  const float* b1 = (const float*)d_in[2];
  const float* W2 = (const float*)d_in[3];
  const float* b2 = (const float*)d_in[4];
  const float* Wout = (const float*)d_in[5];
  const float* bout = (const float*)d_in[6];

  char* ws = (char*)d_ws;
  unsigned short* g1blob = (unsigned short*)(ws + WS_G1BLOB);
  unsigned short* g3blob = (unsigned short*)(ws + WS_G3BLOB);
  unsigned short* woutT  = (unsigned short*)(ws + WS_WOUTT);
  unsigned short* h1ring = (unsigned short*)(ws + WS_H1RING);
  unsigned*       syncb  = (unsigned*)(ws + WS_SYNC);
  unsigned short* h2all  = (unsigned short*)(ws + WS_H2ALL);

  float* outY = (float*)d_out;
  float* outF = outY + 67108864;   // Y then H1,C1,H2,C2

  hipLaunchKernelGGL(k_init, dim3(16), dim3(256), 0, stream, syncb, 4096);
  hipLaunchKernelGGL(k_pack_g1, dim3(2048), dim3(256), 0, stream, W1, g1blob);
  hipLaunchKernelGGL(k_pack_g3, dim3(4096), dim3(256), 0, stream, W2, g3blob);
  hipLaunchKernelGGL(k_pack_woutT, dim3(16384), dim3(256), 0, stream, Wout, woutT);

  hipLaunchKernelGGL(k_lstm, dim3(128), dim3(256), 0, stream,
                     tokens, W1, b1, b2, g1blob, g3blob, h1ring, h2all, outF, syncb);

  hipLaunchKernelGGL(k_gemm_out, dim3(4096), dim3(256), 0, stream, h2all, woutT, bout, outY);
}

// Round 7
// 11988.479 us; speedup vs baseline: 1.4611x; 1.4611x over previous
//
#include <hip/hip_runtime.h>
#include <hip/hip_bf16.h>

typedef float f32x4 __attribute__((ext_vector_type(4)));
typedef short bf16x8 __attribute__((ext_vector_type(8)));

#define MFMA16x32(a,b,c) __builtin_amdgcn_mfma_f32_16x16x32_bf16((a),(b),(c),0,0,0)

__device__ __forceinline__ unsigned short f2bf(float f) {
  unsigned u = __float_as_uint(f);
  u += 0x7fffu + ((u >> 16) & 1u);
  return (unsigned short)(u >> 16);
}

// H stores: relaxed agent-scope = write-through past L2 (no dirty lines -> no
// release fence needed; vmcnt(0) ack means globally visible). Proven in R6.
__device__ __forceinline__ void ast16(unsigned short* p, unsigned short v) {
  __hip_atomic_store(p, v, __ATOMIC_RELAXED, __HIP_MEMORY_SCOPE_AGENT);
}

// ---------------- workspace layout (bytes) ----------------
#define WS_G1BLOB 0ull
#define WS_G3BLOB 8388608ull
#define WS_WOUTT  25165824ull
#define WS_H1RING 33554432ull
#define WS_SYNC   34078720ull
#define WS_H2ALL  34095104ull

#define SLSTRIDE 16   // u32 per sync slot (one 64B line per block)

__global__ void k_init(unsigned* __restrict__ p, int n) {
  int i = blockIdx.x * blockDim.x + threadIdx.x;
  for (; i < n; i += gridDim.x * blockDim.x) p[i] = 0u;
}

// ---------------- pack W1h into per-wave B-fragment blob ----------------
__global__ void k_pack_g1(const float* __restrict__ W1, unsigned short* __restrict__ blob) {
  int gtid = blockIdx.x * 256 + threadIdx.x;      // 524288 threads
  int lane = gtid & 63, kk = (gtid >> 6) & 31, w = gtid >> 11;
  int c = lane & 15, q = lane >> 4;
  int g = c >> 2, h = w * 4 + (c & 3);
  bf16x8 s;
#pragma unroll
  for (int j = 0; j < 8; ++j) {
    int k = kk * 32 + q * 8 + j;
    float v = W1[(size_t)g * 5242880u + (size_t)(4096 + k) * 1024u + h];
    ((unsigned short*)&s)[j] = f2bf(v);
  }
  ((bf16x8*)blob)[(size_t)(w * 32 + kk) * 64 + lane] = s;
}

// ---------------- pack W2 (kk<32 -> W2h rows 1024+, kk>=32 -> W2x rows 0..1023) ----------------
__global__ void k_pack_g3(const float* __restrict__ W2, unsigned short* __restrict__ blob) {
  int gtid = blockIdx.x * 256 + threadIdx.x;      // 1048576 threads
  int lane = gtid & 63, kk = (gtid >> 6) & 63, w = gtid >> 12;
  int c = lane & 15, q = lane >> 4;
  int g = c >> 2, h = w * 4 + (c & 3);
  bf16x8 s;
#pragma unroll
  for (int j = 0; j < 8; ++j) {
    int klocal = (kk & 31) * 32 + q * 8 + j;
    int d = (kk < 32) ? (1024 + klocal) : klocal;
    float v = W2[(size_t)g * 2097152u + (size_t)d * 1024u + h];
    ((unsigned short*)&s)[j] = f2bf(v);
  }
  ((bf16x8*)blob)[(size_t)(w * 64 + kk) * 64 + lane] = s;
}

// ---------------- Wout^T bf16 ----------------
__global__ void k_pack_woutT(const float* __restrict__ Wout, unsigned short* __restrict__ wT) {
  int gtid = blockIdx.x * 256 + threadIdx.x;      // 4,194,304 threads
  int k = gtid & 1023, n = gtid >> 10;
  wT[(size_t)n * 1024 + k] = f2bf(Wout[(size_t)k * 4096 + n]);
}

// ---------------- flag-array sync ----------------
// Poll: lane i polls slot i, RELAXED agent loads (bypass, no per-poll inv).
// FENCE=true adds ONE agent acquire fence (buffer_inv) after the flags flip,
// so subsequent plain cached loads cannot hit stale L1/L2 lines.
template <bool FENCE>
__device__ __forceinline__ void wait_slots(const unsigned* __restrict__ slots,
                                           unsigned epoch, unsigned* __restrict__ poison) {
  if (threadIdx.x < 64) {
    unsigned guard = 0;
    for (;;) {
      unsigned v = __hip_atomic_load(&slots[threadIdx.x * SLSTRIDE],
                                     __ATOMIC_RELAXED, __HIP_MEMORY_SCOPE_AGENT);
      if (__all((int)(v >= epoch))) break;
      __builtin_amdgcn_s_sleep(1);
      if (((++guard) & 1023u) == 0u) {
        if (guard > (1u << 18) ||
            __hip_atomic_load(poison, __ATOMIC_RELAXED, __HIP_MEMORY_SCOPE_AGENT) != 0u) {
          __hip_atomic_store(poison, 1u, __ATOMIC_RELAXED, __HIP_MEMORY_SCOPE_AGENT);
          break;   // fail-visible, never hard-hang
        }
      }
    }
    if (FENCE) __builtin_amdgcn_fence(__ATOMIC_ACQUIRE, "agent");
  }
  __syncthreads();
}

// Publish (fence-free): every thread drains its write-through stores (vmcnt(0)
// => globally visible), block barrier, thread 0 stores flag. No L2 writeback.
__device__ __forceinline__ void publish_slot(unsigned* __restrict__ slots,
                                             int myslot, unsigned epoch) {
  asm volatile("s_waitcnt vmcnt(0)" ::: "memory");
  __syncthreads();
  if (threadIdx.x == 0) {
    __hip_atomic_store(&slots[myslot * SLSTRIDE], epoch,
                       __ATOMIC_RELAXED, __HIP_MEMORY_SCOPE_AGENT);
  }
}

// ---------------- persistent recurrent kernel (128 blocks, two decoupled groups) ----------------
// G1 (blocks 0..63):  H1(t) = ew(gather + H1(t-1)@W1h + b1) -> h1ring[t&3]
// G3 (blocks 64..127): H2(t) = ew(b2 + H1(t)@W2x [phase C, pre-barrier]
//                                  + H2(t-1)@W2h [phase A, post-barrier]) -> h2all[t]
__global__ __launch_bounds__(256, 1) void k_lstm(
    const int* __restrict__ tokens, const float* __restrict__ W1,
    const float* __restrict__ b1, const float* __restrict__ b2,
    const unsigned short* __restrict__ g1blob, const unsigned short* __restrict__ g3blob,
    unsigned short* __restrict__ h1ring, unsigned short* __restrict__ h2all,
    float* __restrict__ outF, unsigned* __restrict__ syncbase)
{
  const int tid = threadIdx.x, lane = tid & 63, widx = tid >> 6, bid = blockIdx.x;
  const int c = lane & 15, q = lane >> 4;
  const bool isG1 = bid < 64;
  const int myslot = isG1 ? bid : bid - 64;
  const int w = myslot * 4 + widx;                    // 0..255 within role
  const int g = c >> 2;
  const int hcol = w * 4 + (c & 3);
  const int h_ew = w * 4 + (lane & 3);

  unsigned* g1slots = syncbase;                       // 64 x 16 u32
  unsigned* g3slots = syncbase + 1024;
  unsigned* poison  = syncbase + 2048;

  // --- preload weight fragments into registers ---
  bf16x8 Breg[64];
  {
    const bf16x8* blob1 = (const bf16x8*)g1blob;
    const bf16x8* blob3 = (const bf16x8*)g3blob;
#pragma unroll
    for (int kk = 0; kk < 32; ++kk)
      Breg[kk] = isG1 ? blob1[(size_t)(w * 32 + kk) * 64 + lane]
                      : blob3[(size_t)(w * 64 + kk) * 64 + lane];
    if (!isG1) {
#pragma unroll
      for (int kk = 32; kk < 64; ++kk)
        Breg[kk] = blob3[(size_t)(w * 64 + kk) * 64 + lane];
    }
  }
  const float biasv = isG1 ? b1[g * 1024 + hcol] : b2[g * 1024 + hcol];

  float Cst[16];
#pragma unroll
  for (int i = 0; i < 16; ++i) Cst[i] = 0.f;

  // --- G1: preload embedding gathers for t=0 ---
  float gv[16];
  if (isG1) {
#pragma unroll
    for (int m = 0; m < 4; ++m)
#pragma unroll
      for (int r = 0; r < 4; ++r) {
        int b_ = m * 16 + q * 4 + r;
        int tk = tokens[b_ * 256];
        gv[m * 4 + r] = W1[(size_t)g * 5242880u + (size_t)tk * 1024u + hcol];
      }
  }

  f32x4 acc[4];

  if (isG1) {
    // ================= G1 chain =================
#pragma clang loop unroll(disable)
    for (int t = 0; t < 256; ++t) {
      if (t > 0) wait_slots<true>(g1slots, (unsigned)t, poison);   // all H1(t-1) visible

      int tk2[16];
      const int tn = (t < 255) ? t + 1 : 255;
#pragma unroll
      for (int m = 0; m < 4; ++m)
#pragma unroll
        for (int r = 0; r < 4; ++r)
          tk2[m * 4 + r] = tokens[(m * 16 + q * 4 + r) * 256 + tn];

#pragma unroll
      for (int m = 0; m < 4; ++m) acc[m] = (f32x4){0.f, 0.f, 0.f, 0.f};
      if (t > 0) {
        const unsigned short* Hrd = h1ring + ((t - 1) & 3) * 65536;
#pragma unroll
        for (int kk = 0; kk < 32; ++kk) {
#pragma unroll
          for (int m = 0; m < 4; ++m) {
            bf16x8 a = *(const bf16x8*)(Hrd + (m * 16 + c) * 1024 + kk * 32 + q * 8);
            acc[m] = MFMA16x32(a, Breg[kk], acc[m]);
          }
        }
      }
      if (t >= 4) wait_slots<false>(g3slots, (unsigned)(t - 3), poison);  // ring backpressure

#pragma unroll
      for (int m = 0; m < 4; ++m) {
#pragma unroll
        for (int r = 0; r < 4; ++r) {
          float v = acc[m][r] + gv[m * 4 + r] + biasv;
          const int sb = (lane & 48) | (lane & 3);
          float vf = __shfl(v, sb, 64);
          float vi = __shfl(v, sb | 4, 64);
          float vo = __shfl(v, sb | 8, 64);
          float vc = __shfl(v, sb | 12, 64);
          float fg = 1.f / (1.f + __expf(-vf));
          float ig = 1.f / (1.f + __expf(-vi));
          float og = 1.f / (1.f + __expf(-vo));
          float e2 = __expf(2.f * vc);
          float ct = (e2 - 1.f) / (e2 + 1.f);
          float Cn = fg * Cst[m * 4 + r] + ig * ct;
          Cst[m * 4 + r] = Cn;
          float e2c = __expf(2.f * Cn);
          float Hn = og * (e2c - 1.f) / (e2c + 1.f);
          if ((lane & 12) == 0) {
            int row = m * 16 + q * 4 + r;
            ast16(&h1ring[(t & 3) * 65536 + row * 1024 + h_ew], f2bf(Hn));
            if (t == 255) {
              outF[row * 1024 + h_ew] = Hn;           // H1 final
              outF[65536 + row * 1024 + h_ew] = Cn;   // C1 final
            }
          }
        }
      }
      publish_slot(g1slots, myslot, (unsigned)(t + 1));      // H1(t) published

      // prefetch next step's embedding gathers (into registers; fence-immune)
#pragma unroll
      for (int i = 0; i < 16; ++i)
        gv[i] = W1[(size_t)g * 5242880u + (size_t)tk2[i] * 1024u + hcol];
    }
  } else {
    // ================= G3 chain =================
#pragma clang loop unroll(disable)
    for (int t = 0; t < 256; ++t) {
      // phase C FIRST: H1(t) is available early (G1 runs up to 3 ahead), so this
      // overlaps with other G3 blocks still finishing step t-1.
      wait_slots<true>(g1slots, (unsigned)(t + 1), poison);
#pragma unroll
      for (int m = 0; m < 4; ++m) acc[m] = (f32x4){biasv, biasv, biasv, biasv};
      {
        const unsigned short* Hrd = h1ring + (t & 3) * 65536;
#pragma unroll
        for (int kk = 32; kk < 64; ++kk) {
#pragma unroll
          for (int m = 0; m < 4; ++m) {
            bf16x8 a = *(const bf16x8*)(Hrd + (m * 16 + c) * 1024 + (kk - 32) * 32 + q * 8);
            acc[m] = MFMA16x32(a, Breg[kk], acc[m]);
          }
        }
      }

      if (t > 0) {
        wait_slots<true>(g3slots, (unsigned)t, poison);      // all H2(t-1) visible
        const unsigned short* Hrd = h2all + (size_t)(t - 1) * 65536;
#pragma unroll
        for (int kk = 0; kk < 32; ++kk) {
#pragma unroll
          for (int m = 0; m < 4; ++m) {
            bf16x8 a = *(const bf16x8*)(Hrd + (m * 16 + c) * 1024 + kk * 32 + q * 8);
            acc[m] = MFMA16x32(a, Breg[kk], acc[m]);
          }
        }
      }

#pragma unroll
      for (int m = 0; m < 4; ++m) {
#pragma unroll
        for (int r = 0; r < 4; ++r) {
          float v = acc[m][r];
          const int sb = (lane & 48) | (lane & 3);
          float vf = __shfl(v, sb, 64);
          float vi = __shfl(v, sb | 4, 64);
          float vo = __shfl(v, sb | 8, 64);
          float vc = __shfl(v, sb | 12, 64);
          float fg = 1.f / (1.f + __expf(-vf));
          float ig = 1.f / (1.f + __expf(-vi));
          float og = 1.f / (1.f + __expf(-vo));
          float e2 = __expf(2.f * vc);
          float ct = (e2 - 1.f) / (e2 + 1.f);
          float Cn = fg * Cst[m * 4 + r] + ig * ct;
          Cst[m * 4 + r] = Cn;
          float e2c = __expf(2.f * Cn);
          float Hn = og * (e2c - 1.f) / (e2c + 1.f);
          if ((lane & 12) == 0) {
            int row = m * 16 + q * 4 + r;
            ast16(&h2all[((size_t)t * 64 + row) * 1024 + h_ew], f2bf(Hn));
            if (t == 255) {
              outF[131072 + row * 1024 + h_ew] = Hn;  // H2 final
              outF[196608 + row * 1024 + h_ew] = Cn;  // C2 final
            }
          }
        }
      }
      publish_slot(g3slots, myslot, (unsigned)(t + 1));      // H2(t) published
    }
  }
}

// ---------------- output projection: Y = H2all @ Wout + bout ----------------
__global__ __launch_bounds__(256, 2) void k_gemm_out(
    const unsigned short* __restrict__ A, const unsigned short* __restrict__ Bt,
    const float* __restrict__ bout, float* __restrict__ C)
{
  __shared__ unsigned short As[128 * 32];
  __shared__ unsigned short Bs[128 * 32];
  const int tid = threadIdx.x, lane = tid & 63, wv = tid >> 6;
  const int c = lane & 15, q = lane >> 4;
  const int bn = blockIdx.x & 31, bm = blockIdx.x >> 5;
  const int wm = wv >> 1, wn = wv & 1;

  f32x4 acc[4][4];
#pragma unroll
  for (int m = 0; m < 4; ++m)
#pragma unroll
    for (int n = 0; n < 4; ++n) acc[m][n] = (f32x4){0.f, 0.f, 0.f, 0.f};

  const unsigned short* Abase = A + (size_t)(bm * 128) * 1024;
  const unsigned short* Bbase = Bt + (size_t)(bn * 128) * 1024;

  for (int kt = 0; kt < 32; ++kt) {
    if (kt) __syncthreads();
#pragma unroll
    for (int ch = 0; ch < 2; ++ch) {
      int o = ch * 4096 + tid * 16;          // byte offset within 8KB tile
      int row = o >> 6;
      int ks = (o & 63) >> 1;
      *(bf16x8*)&As[o >> 1] = *(const bf16x8*)(Abase + (size_t)row * 1024 + kt * 32 + ks);
      *(bf16x8*)&Bs[o >> 1] = *(const bf16x8*)(Bbase + (size_t)row * 1024 + kt * 32 + ks);
    }
    __syncthreads();
    bf16x8 af[4], bfr[4];
#pragma unroll
    for (int m = 0; m < 4; ++m) af[m] = *(const bf16x8*)&As[(wm * 64 + m * 16 + c) * 32 + q * 8];
#pragma unroll
    for (int n = 0; n < 4; ++n) bfr[n] = *(const bf16x8*)&Bs[(wn * 64 + n * 16 + c) * 32 + q * 8];
#pragma unroll
    for (int m = 0; m < 4; ++m)
#pragma unroll
      for (int n = 0; n < 4; ++n) acc[m][n] = MFMA16x32(af[m], bfr[n], acc[m][n]);
  }

#pragma unroll
  for (int n = 0; n < 4; ++n) {
    int col = bn * 128 + wn * 64 + n * 16 + c;
    float bo = bout[col];
#pragma unroll
    for (int m = 0; m < 4; ++m) {
      int row0 = bm * 128 + wm * 64 + m * 16 + q * 4;
#pragma unroll
      for (int r = 0; r < 4; ++r)
        C[(size_t)(row0 + r) * 4096 + col] = acc[m][n][r] + bo;
    }
  }
}

extern "C" void kernel_launch(void* const* d_in, const int* in_sizes, int n_in,
                              void* d_out, int out_size, void* d_ws, size_t ws_size,
                              hipStream_t stream) {
  const int* tokens = (const int*)d_in[0];
  const float* W1 = (const float*)d_in[1];
  const float* b1 = (const float*)d_in[2];
  const float* W2 = (const float*)d_in[3];
  const float* b2 = (const float*)d_in[4];
  const float* Wout = (const float*)d_in[5];
  const float* bout = (const float*)d_in[6];

  char* ws = (char*)d_ws;
  unsigned short* g1blob = (unsigned short*)(ws + WS_G1BLOB);
  unsigned short* g3blob = (unsigned short*)(ws + WS_G3BLOB);
  unsigned short* woutT  = (unsigned short*)(ws + WS_WOUTT);
  unsigned short* h1ring = (unsigned short*)(ws + WS_H1RING);
  unsigned*       syncb  = (unsigned*)(ws + WS_SYNC);
  unsigned short* h2all  = (unsigned short*)(ws + WS_H2ALL);

  float* outY = (float*)d_out;
  float* outF = outY + 67108864;   // Y then H1,C1,H2,C2

  hipLaunchKernelGGL(k_init, dim3(16), dim3(256), 0, stream, syncb, 4096);
  hipLaunchKernelGGL(k_pack_g1, dim3(2048), dim3(256), 0, stream, W1, g1blob);
  hipLaunchKernelGGL(k_pack_g3, dim3(4096), dim3(256), 0, stream, W2, g3blob);
  hipLaunchKernelGGL(k_pack_woutT, dim3(16384), dim3(256), 0, stream, Wout, woutT);

  hipLaunchKernelGGL(k_lstm, dim3(128), dim3(256), 0, stream,
                     tokens, W1, b1, b2, g1blob, g3blob, h1ring, h2all, outF, syncb);

  hipLaunchKernelGGL(k_gemm_out, dim3(4096), dim3(256), 0, stream, h2all, woutT, bout, outY);
}

// Round 8
// 4542.644 us; speedup vs baseline: 3.8561x; 2.6391x over previous
//
#include <hip/hip_runtime.h>
#include <hip/hip_bf16.h>

typedef float f32x4 __attribute__((ext_vector_type(4)));
typedef short bf16x8 __attribute__((ext_vector_type(8)));
typedef unsigned int u32x4 __attribute__((ext_vector_type(4)));

#define MFMA16x32(a,b,c) __builtin_amdgcn_mfma_f32_16x16x32_bf16((a),(b),(c),0,0,0)

__device__ __forceinline__ unsigned short f2bf(float f) {
  unsigned u = __float_as_uint(f);
  u += 0x7fffu + ((u >> 16) & 1u);
  return (unsigned short)(u >> 16);
}

// H stores: relaxed agent-scope = write-through past L2 into L3 (no dirty L2
// lines). vmcnt(0) ack => globally visible. Proven correct in R6/R7.
__device__ __forceinline__ void ast16(unsigned short* p, unsigned short v) {
  __hip_atomic_store(p, v, __ATOMIC_RELAXED, __HIP_MEMORY_SCOPE_AGENT);
}

// L1/L2-bypass 16B load (reads the L3 coherence point directly; pipelined,
// no fence, no atomic-scheduling penalty). Explicit vmcnt before use.
__device__ __forceinline__ u32x4 ld16_bypass(const void* p) {
  u32x4 r;
  asm volatile("global_load_dwordx4 %0, %1, off sc0 sc1" : "=v"(r) : "v"(p) : "memory");
  return r;
}

// ---------------- workspace layout (bytes) ----------------
#define WS_G1BLOB 0ull
#define WS_G3BLOB 8388608ull
#define WS_WOUTT  25165824ull
#define WS_H1RING 33554432ull
#define WS_SYNC   34078720ull
#define WS_H2ALL  34095104ull

#define SLSTRIDE 16   // u32 per sync slot (one 64B line per block)

__global__ void k_init(unsigned* __restrict__ p, int n) {
  int i = blockIdx.x * blockDim.x + threadIdx.x;
  for (; i < n; i += gridDim.x * blockDim.x) p[i] = 0u;
}

// ---------------- pack W1h into per-wave B-fragment blob ----------------
__global__ void k_pack_g1(const float* __restrict__ W1, unsigned short* __restrict__ blob) {
  int gtid = blockIdx.x * 256 + threadIdx.x;      // 524288 threads
  int lane = gtid & 63, kk = (gtid >> 6) & 31, w = gtid >> 11;
  int c = lane & 15, q = lane >> 4;
  int g = c >> 2, h = w * 4 + (c & 3);
  bf16x8 s;
#pragma unroll
  for (int j = 0; j < 8; ++j) {
    int k = kk * 32 + q * 8 + j;
    float v = W1[(size_t)g * 5242880u + (size_t)(4096 + k) * 1024u + h];
    ((unsigned short*)&s)[j] = f2bf(v);
  }
  ((bf16x8*)blob)[(size_t)(w * 32 + kk) * 64 + lane] = s;
}

// ---------------- pack W2 (kk<32 -> W2h rows 1024+, kk>=32 -> W2x rows 0..1023) ----------------
__global__ void k_pack_g3(const float* __restrict__ W2, unsigned short* __restrict__ blob) {
  int gtid = blockIdx.x * 256 + threadIdx.x;      // 1048576 threads
  int lane = gtid & 63, kk = (gtid >> 6) & 63, w = gtid >> 12;
  int c = lane & 15, q = lane >> 4;
  int g = c >> 2, h = w * 4 + (c & 3);
  bf16x8 s;
#pragma unroll
  for (int j = 0; j < 8; ++j) {
    int klocal = (kk & 31) * 32 + q * 8 + j;
    int d = (kk < 32) ? (1024 + klocal) : klocal;
    float v = W2[(size_t)g * 2097152u + (size_t)d * 1024u + h];
    ((unsigned short*)&s)[j] = f2bf(v);
  }
  ((bf16x8*)blob)[(size_t)(w * 64 + kk) * 64 + lane] = s;
}

// ---------------- Wout^T bf16 ----------------
__global__ void k_pack_woutT(const float* __restrict__ Wout, unsigned short* __restrict__ wT) {
  int gtid = blockIdx.x * 256 + threadIdx.x;      // 4,194,304 threads
  int k = gtid & 1023, n = gtid >> 10;
  wT[(size_t)n * 1024 + k] = f2bf(Wout[(size_t)k * 4096 + n]);
}

// ---------------- flag-array sync (completely fence-free) ----------------
__device__ __forceinline__ void wait_slots(const unsigned* __restrict__ slots,
                                           unsigned epoch, unsigned* __restrict__ poison) {
  if (threadIdx.x < 64) {
    unsigned guard = 0;
    for (;;) {
      unsigned v = __hip_atomic_load(&slots[threadIdx.x * SLSTRIDE],
                                     __ATOMIC_RELAXED, __HIP_MEMORY_SCOPE_AGENT);
      if (__all((int)(v >= epoch))) break;
      __builtin_amdgcn_s_sleep(1);
      if (((++guard) & 1023u) == 0u) {
        if (guard > (1u << 18) ||
            __hip_atomic_load(poison, __ATOMIC_RELAXED, __HIP_MEMORY_SCOPE_AGENT) != 0u) {
          __hip_atomic_store(poison, 1u, __ATOMIC_RELAXED, __HIP_MEMORY_SCOPE_AGENT);
          break;   // fail-visible, never hard-hang
        }
      }
    }
  }
  __syncthreads();
}

// Publish: drain write-through stores (=> visible at L3), block barrier, flag store.
__device__ __forceinline__ void publish_slot(unsigned* __restrict__ slots,
                                             int myslot, unsigned epoch) {
  asm volatile("s_waitcnt vmcnt(0)" ::: "memory");
  __syncthreads();
  if (threadIdx.x == 0) {
    __hip_atomic_store(&slots[myslot * SLSTRIDE], epoch,
                       __ATOMIC_RELAXED, __HIP_MEMORY_SCOPE_AGENT);
  }
}

// ---------------- stage 128KB H matrix global->LDS, bypass loads, XOR-swizzled ----
// LDS byte P holds H[row][ (P&2047) ^ ((row&7)<<4) ], row = P>>11.
// (Swizzle folded into SOURCE address; LDS dest linear.)
__device__ __forceinline__ void stage_H(const unsigned short* __restrict__ Hsrc,
                                        unsigned short* __restrict__ Hs) {
  const int tid = threadIdx.x;
  const char* base = (const char*)Hsrc;
  const int rowlo = tid >> 7;          // 0 or 1
  const int x = (tid & 127) * 16;      // byte col within row
#pragma unroll
  for (int b = 0; b < 4; ++b) {        // 4 batches x 8 outstanding loads
    u32x4 v[8];
#pragma unroll
    for (int r8 = 0; r8 < 8; ++r8) {
      int row = (b * 8 + r8) * 2 + rowlo;
      v[r8] = ld16_bypass(base + row * 2048 + (x ^ ((row & 7) << 4)));
    }
    asm volatile("s_waitcnt vmcnt(0)" ::: "memory");
    __builtin_amdgcn_sched_barrier(0);
#pragma unroll
    for (int r8 = 0; r8 < 8; ++r8)
      *(u32x4*)((char*)Hs + (b * 8 + r8) * 4096 + tid * 16) = v[r8];
  }
}

// swizzled LDS fragment read: row, colb(bytes) -> bf16x8 (ds_read_b128, <=2-way conflict)
__device__ __forceinline__ bf16x8 lds_frag(const unsigned short* __restrict__ Hs,
                                           int row, int colb) {
  return *(const bf16x8*)((const char*)Hs + row * 2048 + (colb ^ ((row & 7) << 4)));
}

// ---------------- persistent recurrent kernel (128 blocks, two decoupled groups) ----------------
// G1 (blocks 0..63):  H1(t) = ew(gather + H1(t-1)@W1h + b1) -> h1ring[t&3]
// G3 (blocks 64..127): H2(t) = ew(b2 + H1(t)@W2x + H2(t-1)@W2h) -> h2all[t]
__global__ __launch_bounds__(256, 1) void k_lstm(
    const int* __restrict__ tokens, const float* __restrict__ W1,
    const float* __restrict__ b1, const float* __restrict__ b2,
    const unsigned short* __restrict__ g1blob, const unsigned short* __restrict__ g3blob,
    unsigned short* __restrict__ h1ring, unsigned short* __restrict__ h2all,
    float* __restrict__ outF, unsigned* __restrict__ syncbase)
{
  __shared__ unsigned short Hs[65536];   // 128 KB staging buffer

  const int tid = threadIdx.x, lane = tid & 63, widx = tid >> 6, bid = blockIdx.x;
  const int c = lane & 15, q = lane >> 4;
  const bool isG1 = bid < 64;
  const int myslot = isG1 ? bid : bid - 64;
  const int w = myslot * 4 + widx;                    // 0..255 within role
  const int g = c >> 2;
  const int hcol = w * 4 + (c & 3);
  const int h_ew = w * 4 + (lane & 3);

  unsigned* g1slots = syncbase;                       // 64 x 16 u32
  unsigned* g3slots = syncbase + 1024;
  unsigned* poison  = syncbase + 2048;

  // --- preload weight fragments into registers ---
  bf16x8 Breg[64];
  {
    const bf16x8* blob1 = (const bf16x8*)g1blob;
    const bf16x8* blob3 = (const bf16x8*)g3blob;
#pragma unroll
    for (int kk = 0; kk < 32; ++kk)
      Breg[kk] = isG1 ? blob1[(size_t)(w * 32 + kk) * 64 + lane]
                      : blob3[(size_t)(w * 64 + kk) * 64 + lane];
    if (!isG1) {
#pragma unroll
      for (int kk = 32; kk < 64; ++kk)
        Breg[kk] = blob3[(size_t)(w * 64 + kk) * 64 + lane];
    }
  }
  const float biasv = isG1 ? b1[g * 1024 + hcol] : b2[g * 1024 + hcol];

  float Cst[16];
#pragma unroll
  for (int i = 0; i < 16; ++i) Cst[i] = 0.f;

  // --- G1: preload embedding gathers for t=0 ---
  float gv[16];
  if (isG1) {
#pragma unroll
    for (int m = 0; m < 4; ++m)
#pragma unroll
      for (int r = 0; r < 4; ++r) {
        int b_ = m * 16 + q * 4 + r;
        int tk = tokens[b_ * 256];
        gv[m * 4 + r] = W1[(size_t)g * 5242880u + (size_t)tk * 1024u + hcol];
      }
  }

  f32x4 acc[4];

  if (isG1) {
    // ================= G1 chain =================
#pragma clang loop unroll(disable)
    for (int t = 0; t < 256; ++t) {
      if (t > 0) wait_slots(g1slots, (unsigned)t, poison);   // all H1(t-1) at L3

      int tk2[16];
      const int tn = (t < 255) ? t + 1 : 255;
#pragma unroll
      for (int m = 0; m < 4; ++m)
#pragma unroll
        for (int r = 0; r < 4; ++r)
          tk2[m * 4 + r] = tokens[(m * 16 + q * 4 + r) * 256 + tn];

#pragma unroll
      for (int m = 0; m < 4; ++m) acc[m] = (f32x4){0.f, 0.f, 0.f, 0.f};
      if (t > 0) {
        stage_H(h1ring + ((t - 1) & 3) * 65536, Hs);
        __syncthreads();
#pragma unroll
        for (int kk = 0; kk < 32; ++kk) {
#pragma unroll
          for (int m = 0; m < 4; ++m) {
            bf16x8 a = lds_frag(Hs, m * 16 + c, kk * 64 + q * 16);
            acc[m] = MFMA16x32(a, Breg[kk], acc[m]);
          }
        }
        __syncthreads();   // Hs reads done before next step's staging
      }
      if (t >= 4) wait_slots(g3slots, (unsigned)(t - 3), poison);  // ring backpressure

#pragma unroll
      for (int m = 0; m < 4; ++m) {
#pragma unroll
        for (int r = 0; r < 4; ++r) {
          float v = acc[m][r] + gv[m * 4 + r] + biasv;
          const int sb = (lane & 48) | (lane & 3);
          float vf = __shfl(v, sb, 64);
          float vi = __shfl(v, sb | 4, 64);
          float vo = __shfl(v, sb | 8, 64);
          float vc = __shfl(v, sb | 12, 64);
          float fg = 1.f / (1.f + __expf(-vf));
          float ig = 1.f / (1.f + __expf(-vi));
          float og = 1.f / (1.f + __expf(-vo));
          float e2 = __expf(2.f * vc);
          float ct = (e2 - 1.f) / (e2 + 1.f);
          float Cn = fg * Cst[m * 4 + r] + ig * ct;
          Cst[m * 4 + r] = Cn;
          float e2c = __expf(2.f * Cn);
          float Hn = og * (e2c - 1.f) / (e2c + 1.f);
          if ((lane & 12) == 0) {
            int row = m * 16 + q * 4 + r;
            ast16(&h1ring[(t & 3) * 65536 + row * 1024 + h_ew], f2bf(Hn));
            if (t == 255) {
              outF[row * 1024 + h_ew] = Hn;           // H1 final
              outF[65536 + row * 1024 + h_ew] = Cn;   // C1 final
            }
          }
        }
      }
      publish_slot(g1slots, myslot, (unsigned)(t + 1));      // H1(t) published

      // prefetch next step's embedding gathers (cached reads, overlap next wait)
#pragma unroll
      for (int i = 0; i < 16; ++i)
        gv[i] = W1[(size_t)g * 5242880u + (size_t)tk2[i] * 1024u + hcol];
    }
  } else {
    // ================= G3 chain =================
#pragma clang loop unroll(disable)
    for (int t = 0; t < 256; ++t) {
      // phase C first: H1(t) is available early (G1 runs up to 3 ahead)
      wait_slots(g1slots, (unsigned)(t + 1), poison);
#pragma unroll
      for (int m = 0; m < 4; ++m) acc[m] = (f32x4){biasv, biasv, biasv, biasv};
      stage_H(h1ring + (t & 3) * 65536, Hs);
      __syncthreads();
#pragma unroll
      for (int kk = 32; kk < 64; ++kk) {
#pragma unroll
        for (int m = 0; m < 4; ++m) {
          bf16x8 a = lds_frag(Hs, m * 16 + c, (kk - 32) * 64 + q * 16);
          acc[m] = MFMA16x32(a, Breg[kk], acc[m]);
        }
      }
      __syncthreads();   // Hs reads done before reuse

      if (t > 0) {
        wait_slots(g3slots, (unsigned)t, poison);      // all H2(t-1) at L3
        stage_H(h2all + (size_t)(t - 1) * 65536, Hs);
        __syncthreads();
#pragma unroll
        for (int kk = 0; kk < 32; ++kk) {
#pragma unroll
          for (int m = 0; m < 4; ++m) {
            bf16x8 a = lds_frag(Hs, m * 16 + c, kk * 64 + q * 16);
            acc[m] = MFMA16x32(a, Breg[kk], acc[m]);
          }
        }
        __syncthreads();
      }

#pragma unroll
      for (int m = 0; m < 4; ++m) {
#pragma unroll
        for (int r = 0; r < 4; ++r) {
          float v = acc[m][r];
          const int sb = (lane & 48) | (lane & 3);
          float vf = __shfl(v, sb, 64);
          float vi = __shfl(v, sb | 4, 64);
          float vo = __shfl(v, sb | 8, 64);
          float vc = __shfl(v, sb | 12, 64);
          float fg = 1.f / (1.f + __expf(-vf));
          float ig = 1.f / (1.f + __expf(-vi));
          float og = 1.f / (1.f + __expf(-vo));
          float e2 = __expf(2.f * vc);
          float ct = (e2 - 1.f) / (e2 + 1.f);
          float Cn = fg * Cst[m * 4 + r] + ig * ct;
          Cst[m * 4 + r] = Cn;
          float e2c = __expf(2.f * Cn);
          float Hn = og * (e2c - 1.f) / (e2c + 1.f);
          if ((lane & 12) == 0) {
            int row = m * 16 + q * 4 + r;
            ast16(&h2all[((size_t)t * 64 + row) * 1024 + h_ew], f2bf(Hn));
            if (t == 255) {
              outF[131072 + row * 1024 + h_ew] = Hn;  // H2 final
              outF[196608 + row * 1024 + h_ew] = Cn;  // C2 final
            }
          }
        }
      }
      publish_slot(g3slots, myslot, (unsigned)(t + 1));      // H2(t) published
    }
  }
}

// ---------------- output projection: Y = H2all @ Wout + bout ----------------
__global__ __launch_bounds__(256, 2) void k_gemm_out(
    const unsigned short* __restrict__ A, const unsigned short* __restrict__ Bt,
    const float* __restrict__ bout, float* __restrict__ C)
{
  __shared__ unsigned short As[128 * 32];
  __shared__ unsigned short Bs[128 * 32];
  const int tid = threadIdx.x, lane = tid & 63, wv = tid >> 6;
  const int c = lane & 15, q = lane >> 4;
  const int bn = blockIdx.x & 31, bm = blockIdx.x >> 5;
  const int wm = wv >> 1, wn = wv & 1;

  f32x4 acc[4][4];
#pragma unroll
  for (int m = 0; m < 4; ++m)
#pragma unroll
    for (int n = 0; n < 4; ++n) acc[m][n] = (f32x4){0.f, 0.f, 0.f, 0.f};

  const unsigned short* Abase = A + (size_t)(bm * 128) * 1024;
  const unsigned short* Bbase = Bt + (size_t)(bn * 128) * 1024;

  for (int kt = 0; kt < 32; ++kt) {
    if (kt) __syncthreads();
#pragma unroll
    for (int ch = 0; ch < 2; ++ch) {
      int o = ch * 4096 + tid * 16;          // byte offset within 8KB tile
      int row = o >> 6;
      int ks = (o & 63) >> 1;
      *(bf16x8*)&As[o >> 1] = *(const bf16x8*)(Abase + (size_t)row * 1024 + kt * 32 + ks);
      *(bf16x8*)&Bs[o >> 1] = *(const bf16x8*)(Bbase + (size_t)row * 1024 + kt * 32 + ks);
    }
    __syncthreads();
    bf16x8 af[4], bfr[4];
#pragma unroll
    for (int m = 0; m < 4; ++m) af[m] = *(const bf16x8*)&As[(wm * 64 + m * 16 + c) * 32 + q * 8];
#pragma unroll
    for (int n = 0; n < 4; ++n) bfr[n] = *(const bf16x8*)&Bs[(wn * 64 + n * 16 + c) * 32 + q * 8];
#pragma unroll
    for (int m = 0; m < 4; ++m)
#pragma unroll
      for (int n = 0; n < 4; ++n) acc[m][n] = MFMA16x32(af[m], bfr[n], acc[m][n]);
  }

#pragma unroll
  for (int n = 0; n < 4; ++n) {
    int col = bn * 128 + wn * 64 + n * 16 + c;
    float bo = bout[col];
#pragma unroll
    for (int m = 0; m < 4; ++m) {
      int row0 = bm * 128 + wm * 64 + m * 16 + q * 4;
#pragma unroll
      for (int r = 0; r < 4; ++r)
        C[(size_t)(row0 + r) * 4096 + col] = acc[m][n][r] + bo;
    }
  }
}

extern "C" void kernel_launch(void* const* d_in, const int* in_sizes, int n_in,
                              void* d_out, int out_size, void* d_ws, size_t ws_size,
                              hipStream_t stream) {
  const int* tokens = (const int*)d_in[0];
  const float* W1 = (const float*)d_in[1];
  const float* b1 = (const float*)d_in[2];
  const float* W2 = (const float*)d_in[3];
  const float* b2 = (const float*)d_in[4];
  const float* Wout = (const float*)d_in[5];
  const float* bout = (const float*)d_in[6];

  char* ws = (char*)d_ws;
  unsigned short* g1blob = (unsigned short*)(ws + WS_G1BLOB);
  unsigned short* g3blob = (unsigned short*)(ws + WS_G3BLOB);
  unsigned short* woutT  = (unsigned short*)(ws + WS_WOUTT);
  unsigned short* h1ring = (unsigned short*)(ws + WS_H1RING);
  unsigned*       syncb  = (unsigned*)(ws + WS_SYNC);
  unsigned short* h2all  = (unsigned short*)(ws + WS_H2ALL);

  float* outY = (float*)d_out;
  float* outF = outY + 67108864;   // Y then H1,C1,H2,C2

  hipLaunchKernelGGL(k_init, dim3(16), dim3(256), 0, stream, syncb, 4096);
  hipLaunchKernelGGL(k_pack_g1, dim3(2048), dim3(256), 0, stream, W1, g1blob);
  hipLaunchKernelGGL(k_pack_g3, dim3(4096), dim3(256), 0, stream, W2, g3blob);
  hipLaunchKernelGGL(k_pack_woutT, dim3(16384), dim3(256), 0, stream, Wout, woutT);

  hipLaunchKernelGGL(k_lstm, dim3(128), dim3(256), 0, stream,
                     tokens, W1, b1, b2, g1blob, g3blob, h1ring, h2all, outF, syncb);

  hipLaunchKernelGGL(k_gemm_out, dim3(4096), dim3(256), 0, stream, h2all, woutT, bout, outY);
}